// Round 1
// 299.809 us; speedup vs baseline: 1.0076x; 1.0076x over previous
//
#include <hip/hip_runtime.h>
#include <cmath>

#define BB 8
#define LL 512
#define HH 512

typedef __attribute__((ext_vector_type(8))) short short8;
typedef __attribute__((ext_vector_type(4))) float floatx4;

__device__ __forceinline__ unsigned short f2bf(float x) {
  unsigned int u = __float_as_uint(x);
  unsigned int r = (u + 0x7fffu + ((u >> 16) & 1u)) >> 16;
  return (unsigned short)r;
}

// ---------------- K0a: convert Bm,C to bf16, normal + transposed ----------------
__global__ __launch_bounds__(256) void k0_conv(
    const float* __restrict__ Bm, const float* __restrict__ C,
    unsigned short* __restrict__ Bn, unsigned short* __restrict__ Cn,
    unsigned short* __restrict__ Bt, unsigned short* __restrict__ Ct) {
  __shared__ unsigned short tile[64][68];
  int bid = blockIdx.x;            // 1024
  int s = bid >> 9;
  int rem = bid & 511;
  int b = rem >> 6, tr = (rem >> 3) & 7, tc = rem & 7;
  const float* src = s ? C : Bm;
  unsigned short* dn = s ? Cn : Bn;
  unsigned short* dt = s ? Ct : Bt;
  int t = threadIdx.x;
  int r0 = t >> 4, c0 = (t & 15) * 4;
#pragma unroll
  for (int rr = 0; rr < 4; ++rr) {
    int r = rr * 16 + r0;
    const float* sp = src + ((size_t)(b * 512 + tr * 64 + r)) * 512 + tc * 64 + c0;
    float4 v = *(const float4*)sp;
    unsigned short h0 = f2bf(v.x), h1 = f2bf(v.y), h2 = f2bf(v.z), h3 = f2bf(v.w);
    unsigned short* np = dn + ((size_t)(b * 512 + tr * 64 + r)) * 512 + tc * 64 + c0;
    np[0] = h0; np[1] = h1; np[2] = h2; np[3] = h3;
    tile[r][c0] = h0; tile[r][c0 + 1] = h1; tile[r][c0 + 2] = h2; tile[r][c0 + 3] = h3;
  }
  __syncthreads();
  int d = t & 63, j0 = (t >> 6) * 16;
  short8 v0, v1;
#pragma unroll
  for (int e = 0; e < 8; ++e) v0[e] = (short)tile[j0 + e][d];
#pragma unroll
  for (int e = 0; e < 8; ++e) v1[e] = (short)tile[j0 + 8 + e][d];
  unsigned short* tp = dt + ((size_t)(b * 512 + tc * 64 + d)) * 512 + tr * 64 + j0;
  *(short8*)tp = v0;
  *(short8*)(tp + 8) = v1;
}

// ---------------- K0b: Xm_p = bf16(X .* wM_p) ----------------
__global__ __launch_bounds__(256) void k0_xm(
    const float* __restrict__ A, const float* __restrict__ Bm,
    const float* __restrict__ w0, const float* __restrict__ w1, const float* __restrict__ w2,
    unsigned short* __restrict__ Xm0, unsigned short* __restrict__ Xm1,
    unsigned short* __restrict__ Xm2) {
  unsigned int idx = blockIdx.x * 256 + threadIdx.x;   // 786432 threads
  size_t e0 = (size_t)idx * 8;
  int k0 = (int)(e0 & 511);
  unsigned int ri = (unsigned int)(e0 >> 9);  // p*4096 + b*512 + i
  int p = ri >> 12;
  unsigned int rowi = ri & 4095;
  const float* X = (p == 2) ? Bm : A;
  const float* wm = ((p == 0) ? w0 : (p == 1) ? w1 : w2) + 2 * HH;
  const float* xp = X + (size_t)rowi * 512 + k0;
  float4 a = *(const float4*)xp, b4 = *(const float4*)(xp + 4);
  float4 wa = *(const float4*)(wm + k0), wb = *(const float4*)(wm + k0 + 4);
  short8 o;
  o[0] = (short)f2bf(a.x * wa.x); o[1] = (short)f2bf(a.y * wa.y);
  o[2] = (short)f2bf(a.z * wa.z); o[3] = (short)f2bf(a.w * wa.w);
  o[4] = (short)f2bf(b4.x * wb.x); o[5] = (short)f2bf(b4.y * wb.y);
  o[6] = (short)f2bf(b4.z * wb.z); o[7] = (short)f2bf(b4.w * wb.w);
  unsigned short* op = ((p == 0) ? Xm0 : (p == 1) ? Xm1 : Xm2) + (size_t)rowi * 512 + k0;
  *(short8*)op = o;
}

// ---------------- K1: row/col bias terms (each row read once, 2 dots) ----------------
__global__ __launch_bounds__(256) void k1_terms(
    const float* __restrict__ A, const float* __restrict__ Bm, const float* __restrict__ C,
    const float* __restrict__ w0, const float* __restrict__ w1, const float* __restrict__ w2,
    float* __restrict__ rowterm, float* __restrict__ colterm) {
  int tid = threadIdx.x;
  int wave = blockIdx.x * 4 + (tid >> 6);   // 0..12287
  int lane = tid & 63;
  int m = wave >> 12;
  int rem = wave & 4095;
  int b = rem >> 9, i = rem & 511;
  const float* src = (m == 0) ? A : (m == 1 ? Bm : C);
  const float *wva, *wvb;
  float *da, *db;
  if (m == 0) {
    wva = w0;      wvb = w1;
    da = rowterm + (0 * BB + b) * LL + i;  db = rowterm + (1 * BB + b) * LL + i;
  } else if (m == 1) {
    wva = w0 + HH; wvb = w2;
    da = colterm + (0 * BB + b) * LL + i;  db = rowterm + (2 * BB + b) * LL + i;
  } else {
    wva = w1 + HH; wvb = w2 + HH;
    da = colterm + (1 * BB + b) * LL + i;  db = colterm + (2 * BB + b) * LL + i;
  }
  const float* row = src + ((size_t)b * LL + i) * HH;
  float a1 = 0.f, a2 = 0.f;
#pragma unroll
  for (int t = 0; t < 8; ++t) {
    float x = row[t * 64 + lane];
    a1 += x * wva[t * 64 + lane];
    a2 += x * wvb[t * 64 + lane];
  }
#pragma unroll
  for (int off = 32; off; off >>= 1) {
    a1 += __shfl_xor(a1, off, 64);
    a2 += __shfl_xor(a2, off, 64);
  }
  if (lane == 0) { *da = a1; *db = a2; }
}

// ---------------- K2: fused MFMA pair-attention, ring-4 software pipeline ----------------
// 16 rows/block, 768 blocks x 512 threads (8 waves, each a 64-col slice).
// __launch_bounds__(512,4): VGPR cap 128 -> deep register prefetch (ring of 4
// 20-VGPR units keeps ~15 independent 1KB loads in flight per wave).
// XCD swizzle: each XCD owns 3 complete (p,b) groups -> Yn+Yt (3MB) L2-resident.
__global__ __launch_bounds__(512, 4) void k2_mfma(
    const unsigned short* __restrict__ Xm0, const unsigned short* __restrict__ Xm1,
    const unsigned short* __restrict__ Xm2,
    const unsigned short* __restrict__ Bn, const unsigned short* __restrict__ Cn,
    const unsigned short* __restrict__ Bt, const unsigned short* __restrict__ Ct,
    const float* __restrict__ A, const float* __restrict__ Bm,
    const float* __restrict__ rowterm, const float* __restrict__ colterm,
    float* __restrict__ mrow, float* __restrict__ out) {
  __shared__ unsigned short P_lds[16 * 512];
  __shared__ float sm_m[8 * 16];
  __shared__ float sm_l[8 * 16];

  int tid = threadIdx.x;
  int bid0 = blockIdx.x;
  // bijective XCD-contiguous remap: XCD x = bid0&7 gets logical ids x*96..x*96+95
  // = 3 full (p,b) groups of 32 row-blocks (768 % 8 == 0).
  int bid = (bid0 & 7) * 96 + (bid0 >> 3);
  int p = bid >> 8;            // 3
  int rem = bid & 255;
  int b = rem >> 5;            // 8
  int rb = rem & 31;           // 32 row-groups of 16
  int i0 = rb * 16;

  const unsigned short* Xmp = (p == 0) ? Xm0 : ((p == 1) ? Xm1 : Xm2);
  const unsigned short* Yn  = (p == 0) ? Bn : Cn;
  const unsigned short* Yt  = (p == 0) ? Bt : Ct;
  const float* X = (p == 2) ? Bm : A;

  int wc = tid >> 6;           // wave 0..7 -> 64-col slice
  int lane = tid & 63;
  int n16 = lane & 15, q = lane >> 4;

  int arow = i0 + n16;
  const unsigned short* ap = Xmp + ((size_t)(b * LL + arow)) * HH;

  // ---- Phase 1: S = Xm @ Yn^T (cols wc*64 .. wc*64+63), ring-4 pipeline ----
  const unsigned short* br0 = Yn + ((size_t)(b * LL + wc * 64 + n16)) * HH;
  const unsigned short* br1 = br0 + (size_t)16 * HH;
  const unsigned short* br2 = br0 + (size_t)32 * HH;
  const unsigned short* br3 = br0 + (size_t)48 * HH;

  floatx4 acc[4] = {};
  short8 p1a0, p1a1, p1a2, p1a3;
  short8 p1b0[4], p1b1[4], p1b2[4], p1b3[4];

#define P1_LOAD(AF, BF, u) do { \
    const int k0_ = (u) * 32 + q * 8; \
    AF = *(const short8*)(ap + k0_); \
    BF[0] = *(const short8*)(br0 + k0_); \
    BF[1] = *(const short8*)(br1 + k0_); \
    BF[2] = *(const short8*)(br2 + k0_); \
    BF[3] = *(const short8*)(br3 + k0_); \
  } while (0)
#define P1_MFMA(AF, BF) do { \
    acc[0] = __builtin_amdgcn_mfma_f32_16x16x32_bf16(AF, BF[0], acc[0], 0, 0, 0); \
    acc[1] = __builtin_amdgcn_mfma_f32_16x16x32_bf16(AF, BF[1], acc[1], 0, 0, 0); \
    acc[2] = __builtin_amdgcn_mfma_f32_16x16x32_bf16(AF, BF[2], acc[2], 0, 0, 0); \
    acc[3] = __builtin_amdgcn_mfma_f32_16x16x32_bf16(AF, BF[3], acc[3], 0, 0, 0); \
  } while (0)

  P1_LOAD(p1a0, p1b0, 0);
  P1_LOAD(p1a1, p1b1, 1);
  P1_LOAD(p1a2, p1b2, 2);
  P1_MFMA(p1a0, p1b0); P1_LOAD(p1a3, p1b3, 3);
  P1_MFMA(p1a1, p1b1); P1_LOAD(p1a0, p1b0, 4);
  P1_MFMA(p1a2, p1b2); P1_LOAD(p1a1, p1b1, 5);
  P1_MFMA(p1a3, p1b3); P1_LOAD(p1a2, p1b2, 6);
  P1_MFMA(p1a0, p1b0); P1_LOAD(p1a3, p1b3, 7);
  P1_MFMA(p1a1, p1b1); P1_LOAD(p1a0, p1b0, 8);
  P1_MFMA(p1a2, p1b2); P1_LOAD(p1a1, p1b1, 9);
  P1_MFMA(p1a3, p1b3); P1_LOAD(p1a2, p1b2, 10);
  P1_MFMA(p1a0, p1b0); P1_LOAD(p1a3, p1b3, 11);
  P1_MFMA(p1a1, p1b1); P1_LOAD(p1a0, p1b0, 12);
  P1_MFMA(p1a2, p1b2); P1_LOAD(p1a1, p1b1, 13);
  P1_MFMA(p1a3, p1b3); P1_LOAD(p1a2, p1b2, 14);
  P1_MFMA(p1a0, p1b0); P1_LOAD(p1a3, p1b3, 15);
  P1_MFMA(p1a1, p1b1);
  P1_MFMA(p1a2, p1b2);
  P1_MFMA(p1a3, p1b3);
#undef P1_LOAD
#undef P1_MFMA

  // ---- Softmax: per-wave 64-col stats + 8-wave LDS combine ----
  float rt[4], rinv[4], ctv[4], mh[4];
  {
    const float* rtp = rowterm + (p * BB + b) * LL + i0 + q * 4;
#pragma unroll
    for (int r = 0; r < 4; ++r) rt[r] = rtp[r];
    const float* ctp = colterm + (p * BB + b) * LL;
#pragma unroll
    for (int f = 0; f < 4; ++f) ctv[f] = ctp[wc * 64 + f * 16 + n16];
  }
#pragma unroll
  for (int r = 0; r < 4; ++r) {
    float m = -1e30f;
#pragma unroll
    for (int f = 0; f < 4; ++f) {
      float v = acc[f][r] + rt[r] + ctv[f];
      acc[f][r] = v;
      m = fmaxf(m, v);
    }
    m = fmaxf(m, __shfl_xor(m, 1, 64));
    m = fmaxf(m, __shfl_xor(m, 2, 64));
    m = fmaxf(m, __shfl_xor(m, 4, 64));
    m = fmaxf(m, __shfl_xor(m, 8, 64));
    mh[r] = m;
  }
  if (n16 == 0) {
#pragma unroll
    for (int r = 0; r < 4; ++r) sm_m[wc * 16 + q * 4 + r] = mh[r];
  }
  __syncthreads();
  float ml[4];
#pragma unroll
  for (int r = 0; r < 4; ++r) {
    float m = mh[r];
#pragma unroll
    for (int k = 0; k < 8; ++k) m = fmaxf(m, sm_m[k * 16 + q * 4 + r]);
    mh[r] = m;
    float l = 0.f;
#pragma unroll
    for (int f = 0; f < 4; ++f) {
      float pv = __expf(acc[f][r] - m);
      acc[f][r] = pv;
      l += pv;
    }
    l += __shfl_xor(l, 1, 64);
    l += __shfl_xor(l, 2, 64);
    l += __shfl_xor(l, 4, 64);
    l += __shfl_xor(l, 8, 64);
    ml[r] = l;
  }
  if (n16 == 0) {
#pragma unroll
    for (int r = 0; r < 4; ++r) sm_l[wc * 16 + q * 4 + r] = ml[r];
    if (wc == 0) {
#pragma unroll
      for (int r = 0; r < 4; ++r)
        mrow[(p * BB + b) * LL + i0 + q * 4 + r] = mh[r];
    }
  }
  __syncthreads();
#pragma unroll
  for (int r = 0; r < 4; ++r) {
    float lf = 0.f;
#pragma unroll
    for (int k = 0; k < 8; ++k) lf += sm_l[k * 16 + q * 4 + r];
    rinv[r] = 1.f / lf;
  }

  // ---- P -> LDS (bf16, unnormalized, XOR-swizzled 8-short chunks) ----
#pragma unroll
  for (int f = 0; f < 4; ++f) {
    int c = wc * 8 + f * 2 + (n16 >> 3);
#pragma unroll
    for (int r = 0; r < 4; ++r) {
      int row = q * 4 + r;
      int pc = c ^ (row & 7);
      P_lds[row * 512 + pc * 8 + (n16 & 7)] = f2bf(acc[f][r]);
    }
  }
  __syncthreads();

  // ---- Phase 2: O = P @ Y (B from Yt), d in wc's 64-col slice, ring-4 ----
  int secoff, colbase;
  if      (p == 0) { secoff = 0;   colbase = 512;  }
  else if (p == 1) { secoff = 0;   colbase = 1024; }
  else             { secoff = 512; colbase = 1024; }

  int prow = n16;
  const unsigned short* tr0 = Yt + ((size_t)(b * LL + wc * 64 + n16)) * HH;
  const unsigned short* tr1 = tr0 + (size_t)16 * HH;
  const unsigned short* tr2 = tr0 + (size_t)32 * HH;
  const unsigned short* tr3 = tr0 + (size_t)48 * HH;
  const unsigned short* pl = &P_lds[prow * 512];

  floatx4 oacc[4] = {};
  short8 p2p0, p2p1, p2p2, p2p3;
  short8 p2b0[4], p2b1[4], p2b2[4], p2b3[4];

#define P2_LOAD(PF, BF, kj) do { \
    const int pc_ = ((((kj) * 4 + q) ^ (prow & 7)) * 8); \
    PF = *(const short8*)(pl + pc_); \
    const int j0_ = (kj) * 32 + q * 8; \
    BF[0] = *(const short8*)(tr0 + j0_); \
    BF[1] = *(const short8*)(tr1 + j0_); \
    BF[2] = *(const short8*)(tr2 + j0_); \
    BF[3] = *(const short8*)(tr3 + j0_); \
  } while (0)
#define P2_MFMA(PF, BF) do { \
    oacc[0] = __builtin_amdgcn_mfma_f32_16x16x32_bf16(PF, BF[0], oacc[0], 0, 0, 0); \
    oacc[1] = __builtin_amdgcn_mfma_f32_16x16x32_bf16(PF, BF[1], oacc[1], 0, 0, 0); \
    oacc[2] = __builtin_amdgcn_mfma_f32_16x16x32_bf16(PF, BF[2], oacc[2], 0, 0, 0); \
    oacc[3] = __builtin_amdgcn_mfma_f32_16x16x32_bf16(PF, BF[3], oacc[3], 0, 0, 0); \
  } while (0)

  P2_LOAD(p2p0, p2b0, 0);
  P2_LOAD(p2p1, p2b1, 1);
  P2_LOAD(p2p2, p2b2, 2);
  P2_MFMA(p2p0, p2b0); P2_LOAD(p2p3, p2b3, 3);
  P2_MFMA(p2p1, p2b1); P2_LOAD(p2p0, p2b0, 4);
  P2_MFMA(p2p2, p2b2); P2_LOAD(p2p1, p2b1, 5);
  P2_MFMA(p2p3, p2b3); P2_LOAD(p2p2, p2b2, 6);
  P2_MFMA(p2p0, p2b0); P2_LOAD(p2p3, p2b3, 7);
  P2_MFMA(p2p1, p2b1); P2_LOAD(p2p0, p2b0, 8);
  P2_MFMA(p2p2, p2b2); P2_LOAD(p2p1, p2b1, 9);
  P2_MFMA(p2p3, p2b3); P2_LOAD(p2p2, p2b2, 10);
  P2_MFMA(p2p0, p2b0); P2_LOAD(p2p3, p2b3, 11);
  P2_MFMA(p2p1, p2b1); P2_LOAD(p2p0, p2b0, 12);
  P2_MFMA(p2p2, p2b2); P2_LOAD(p2p1, p2b1, 13);
  P2_MFMA(p2p3, p2b3); P2_LOAD(p2p2, p2b2, 14);
  P2_MFMA(p2p0, p2b0); P2_LOAD(p2p3, p2b3, 15);
  P2_MFMA(p2p1, p2b1);
  P2_MFMA(p2p2, p2b2);
  P2_MFMA(p2p3, p2b3);
#undef P2_LOAD
#undef P2_MFMA

#pragma unroll
  for (int f = 0; f < 4; ++f) {
    int d = wc * 64 + f * 16 + n16;
#pragma unroll
    for (int r = 0; r < 4; ++r) {
      int ig = i0 + q * 4 + r;
      float val = oacc[f][r] * rinv[r];
      size_t ob = ((size_t)b * 1536 + secoff + ig) * 2560;
      out[ob + colbase + d] = val;
      out[ob + colbase + 1024 + d] = X[((size_t)b * LL + ig) * HH + d] * val;
    }
  }
}

// ---------------- K3: beta softmax + weighted row-sum (192 blocks) ----------------
__global__ __launch_bounds__(256) void k3_beta(
    const float* __restrict__ A, const float* __restrict__ Bm,
    const float* __restrict__ mrow, float* __restrict__ vvec) {
  __shared__ float red[256];
  __shared__ float beta[LL];
  __shared__ float s_inv;
  int blk = blockIdx.x;           // 192
  int p = blk >> 6;
  int rem2 = blk & 63;
  int b = rem2 >> 3;
  int dch = rem2 & 7;
  int tid = threadIdx.x;
  const float* m = mrow + (p * BB + b) * LL;
  red[tid] = fmaxf(m[tid], m[tid + 256]);
  __syncthreads();
  for (int off = 128; off; off >>= 1) {
    if (tid < off) red[tid] = fmaxf(red[tid], red[tid + off]);
    __syncthreads();
  }
  float mx = red[0];
  __syncthreads();
  float e0 = __expf(m[tid] - mx), e1 = __expf(m[tid + 256] - mx);
  beta[tid] = e0; beta[tid + 256] = e1;
  red[tid] = e0 + e1;
  __syncthreads();
  for (int off = 128; off; off >>= 1) {
    if (tid < off) red[tid] += red[tid + off];
    __syncthreads();
  }
  if (tid == 0) s_inv = 1.f / red[0];
  __syncthreads();
  const float* Xb = ((p == 2) ? Bm : A) + (size_t)b * LL * HH;
  int d = dch * 64 + (tid & 63);
  int ig = tid >> 6;
  float acc = 0.f;
  for (int i = ig * 128; i < ig * 128 + 128; ++i)
    acc += beta[i] * Xb[(size_t)i * HH + d];
  red[tid] = acc;
  __syncthreads();
  if (tid < 64) {
    float s = red[tid] + red[tid + 64] + red[tid + 128] + red[tid + 192];
    vvec[(p * BB + b) * HH + dch * 64 + tid] = s * s_inv;
  }
}

// ---------------- K4: finalize, float4, only needed slices ----------------
__global__ __launch_bounds__(256) void k4_finalize(
    const float* __restrict__ A, const float* __restrict__ Bm, const float* __restrict__ C,
    const float* __restrict__ vvec, float* __restrict__ out) {
  unsigned int idx = blockIdx.x * 256 + threadIdx.x;   // 4718592 threads
  int f4 = idx & 127;
  int i  = (idx >> 7) & 511;
  unsigned int ub = idx >> 16;
  unsigned int u = ub % 9;
  unsigned int b = ub / 9;
  int sec, slice;
  if (u == 0)      { sec = 0; slice = 0; }
  else if (u <= 3) { sec = 1; slice = (u == 1) ? 0 : (u == 2 ? 1 : 3); }
  else             { sec = 2; slice = (int)u - 4; }
  int cc = f4 * 4;
  const float* enc = sec == 0 ? A : (sec == 1 ? Bm : C);
  float4 val;
  if (slice == 0) {
    // copy slice: needs enc only
    val = *(const float4*)(enc + ((size_t)b * LL + i) * HH + cc);
  } else {
    int vp = (sec == 1) ? 0 : ((slice == 1 || slice == 3) ? 1 : 2);
    float4 v = *(const float4*)(vvec + (vp * BB + b) * HH + cc);
    if (slice <= 2) {
      // broadcast slice: skip the enc load entirely (block-uniform branch)
      val = v;
    } else {
      float4 e = *(const float4*)(enc + ((size_t)b * LL + i) * HH + cc);
      val.x = e.x * v.x; val.y = e.y * v.y; val.z = e.z * v.z; val.w = e.w * v.w;
    }
  }
  *(float4*)(out + ((size_t)b * 1536 + sec * 512 + i) * 2560 + slice * 512 + cc) = val;
}

extern "C" void kernel_launch(void* const* d_in, const int* in_sizes, int n_in,
                              void* d_out, int out_size, void* d_ws, size_t ws_size,
                              hipStream_t stream) {
  const float* A  = (const float*)d_in[0];
  const float* Bm = (const float*)d_in[1];
  const float* C  = (const float*)d_in[2];
  const float* w0 = (const float*)d_in[3];
  const float* w1 = (const float*)d_in[4];
  const float* w2 = (const float*)d_in[5];
  float* out = (float*)d_out;

  float* wsf = (float*)d_ws;
  float* rowterm = wsf;
  float* colterm = wsf + 12288;
  float* mrow    = wsf + 24576;
  float* vvec    = wsf + 36864;
  unsigned short* wss = (unsigned short*)(wsf + 49152);
  const size_t MSZ = (size_t)BB * LL * HH;     // 2,097,152
  unsigned short* Bn  = wss;
  unsigned short* Cn  = wss + MSZ;
  unsigned short* Bt  = wss + 2 * MSZ;
  unsigned short* Ct  = wss + 3 * MSZ;
  unsigned short* Xm0 = wss + 4 * MSZ;
  unsigned short* Xm1 = wss + 5 * MSZ;
  unsigned short* Xm2 = wss + 6 * MSZ;

  k0_conv<<<1024, 256, 0, stream>>>(Bm, C, Bn, Cn, Bt, Ct);
  k0_xm<<<3072, 256, 0, stream>>>(A, Bm, w0, w1, w2, Xm0, Xm1, Xm2);
  k1_terms<<<3072, 256, 0, stream>>>(A, Bm, C, w0, w1, w2, rowterm, colterm);
  k2_mfma<<<768, 512, 0, stream>>>(Xm0, Xm1, Xm2, Bn, Cn, Bt, Ct, A, Bm,
                                   rowterm, colterm, mrow, out);
  k3_beta<<<192, 256, 0, stream>>>(A, Bm, mrow, vvec);
  k4_finalize<<<18432, 256, 0, stream>>>(A, Bm, C, vvec, out);
}

// Round 2
// 223.599 us; speedup vs baseline: 1.3511x; 1.3408x over previous
//
#include <hip/hip_runtime.h>
#include <cmath>

#define BB 8
#define LL 512
#define HH 512

typedef __attribute__((ext_vector_type(8))) short short8;
typedef __attribute__((ext_vector_type(4))) float floatx4;

#define MM __builtin_amdgcn_mfma_f32_16x16x32_bf16
#define SB() __builtin_amdgcn_sched_barrier(0)

__device__ __forceinline__ unsigned short f2bf(float x) {
  unsigned int u = __float_as_uint(x);
  unsigned int r = (u + 0x7fffu + ((u >> 16) & 1u)) >> 16;
  return (unsigned short)r;
}

// ---------------- K0a: convert Bm,C to bf16, normal + transposed ----------------
__global__ __launch_bounds__(256) void k0_conv(
    const float* __restrict__ Bm, const float* __restrict__ C,
    unsigned short* __restrict__ Bn, unsigned short* __restrict__ Cn,
    unsigned short* __restrict__ Bt, unsigned short* __restrict__ Ct) {
  __shared__ unsigned short tile[64][68];
  int bid = blockIdx.x;            // 1024
  int s = bid >> 9;
  int rem = bid & 511;
  int b = rem >> 6, tr = (rem >> 3) & 7, tc = rem & 7;
  const float* src = s ? C : Bm;
  unsigned short* dn = s ? Cn : Bn;
  unsigned short* dt = s ? Ct : Bt;
  int t = threadIdx.x;
  int r0 = t >> 4, c0 = (t & 15) * 4;
#pragma unroll
  for (int rr = 0; rr < 4; ++rr) {
    int r = rr * 16 + r0;
    const float* sp = src + ((size_t)(b * 512 + tr * 64 + r)) * 512 + tc * 64 + c0;
    float4 v = *(const float4*)sp;
    unsigned short h0 = f2bf(v.x), h1 = f2bf(v.y), h2 = f2bf(v.z), h3 = f2bf(v.w);
    unsigned short* np = dn + ((size_t)(b * 512 + tr * 64 + r)) * 512 + tc * 64 + c0;
    np[0] = h0; np[1] = h1; np[2] = h2; np[3] = h3;
    tile[r][c0] = h0; tile[r][c0 + 1] = h1; tile[r][c0 + 2] = h2; tile[r][c0 + 3] = h3;
  }
  __syncthreads();
  int d = t & 63, j0 = (t >> 6) * 16;
  short8 v0, v1;
#pragma unroll
  for (int e = 0; e < 8; ++e) v0[e] = (short)tile[j0 + e][d];
#pragma unroll
  for (int e = 0; e < 8; ++e) v1[e] = (short)tile[j0 + 8 + e][d];
  unsigned short* tp = dt + ((size_t)(b * 512 + tc * 64 + d)) * 512 + tr * 64 + j0;
  *(short8*)tp = v0;
  *(short8*)(tp + 8) = v1;
}

// ---------------- K0b: Xm_p = bf16(X .* wM_p) ----------------
__global__ __launch_bounds__(256) void k0_xm(
    const float* __restrict__ A, const float* __restrict__ Bm,
    const float* __restrict__ w0, const float* __restrict__ w1, const float* __restrict__ w2,
    unsigned short* __restrict__ Xm0, unsigned short* __restrict__ Xm1,
    unsigned short* __restrict__ Xm2) {
  unsigned int idx = blockIdx.x * 256 + threadIdx.x;   // 786432 threads
  size_t e0 = (size_t)idx * 8;
  int k0 = (int)(e0 & 511);
  unsigned int ri = (unsigned int)(e0 >> 9);  // p*4096 + b*512 + i
  int p = ri >> 12;
  unsigned int rowi = ri & 4095;
  const float* X = (p == 2) ? Bm : A;
  const float* wm = ((p == 0) ? w0 : (p == 1) ? w1 : w2) + 2 * HH;
  const float* xp = X + (size_t)rowi * 512 + k0;
  float4 a = *(const float4*)xp, b4 = *(const float4*)(xp + 4);
  float4 wa = *(const float4*)(wm + k0), wb = *(const float4*)(wm + k0 + 4);
  short8 o;
  o[0] = (short)f2bf(a.x * wa.x); o[1] = (short)f2bf(a.y * wa.y);
  o[2] = (short)f2bf(a.z * wa.z); o[3] = (short)f2bf(a.w * wa.w);
  o[4] = (short)f2bf(b4.x * wb.x); o[5] = (short)f2bf(b4.y * wb.y);
  o[6] = (short)f2bf(b4.z * wb.z); o[7] = (short)f2bf(b4.w * wb.w);
  unsigned short* op = ((p == 0) ? Xm0 : (p == 1) ? Xm1 : Xm2) + (size_t)rowi * 512 + k0;
  *(short8*)op = o;
}

// ---------------- K1: row/col bias terms (each row read once, 2 dots) ----------------
__global__ __launch_bounds__(256) void k1_terms(
    const float* __restrict__ A, const float* __restrict__ Bm, const float* __restrict__ C,
    const float* __restrict__ w0, const float* __restrict__ w1, const float* __restrict__ w2,
    float* __restrict__ rowterm, float* __restrict__ colterm) {
  int tid = threadIdx.x;
  int wave = blockIdx.x * 4 + (tid >> 6);   // 0..12287
  int lane = tid & 63;
  int m = wave >> 12;
  int rem = wave & 4095;
  int b = rem >> 9, i = rem & 511;
  const float* src = (m == 0) ? A : (m == 1 ? Bm : C);
  const float *wva, *wvb;
  float *da, *db;
  if (m == 0) {
    wva = w0;      wvb = w1;
    da = rowterm + (0 * BB + b) * LL + i;  db = rowterm + (1 * BB + b) * LL + i;
  } else if (m == 1) {
    wva = w0 + HH; wvb = w2;
    da = colterm + (0 * BB + b) * LL + i;  db = rowterm + (2 * BB + b) * LL + i;
  } else {
    wva = w1 + HH; wvb = w2 + HH;
    da = colterm + (1 * BB + b) * LL + i;  db = colterm + (2 * BB + b) * LL + i;
  }
  const float* row = src + ((size_t)b * LL + i) * HH;
  float a1 = 0.f, a2 = 0.f;
#pragma unroll
  for (int t = 0; t < 8; ++t) {
    float x = row[t * 64 + lane];
    a1 += x * wva[t * 64 + lane];
    a2 += x * wvb[t * 64 + lane];
  }
#pragma unroll
  for (int off = 32; off; off >>= 1) {
    a1 += __shfl_xor(a1, off, 64);
    a2 += __shfl_xor(a2, off, 64);
  }
  if (lane == 0) { *da = a1; *db = a2; }
}

// ---------------- K2: fused MFMA pair-attention, 64-row tiles ----------------
// 192 blocks (= 8 XCD x 24) x 512 threads (8 waves, each a 64-col slice).
// A staged in 64KB XOR-swizzled LDS (re-used for softmax combine, then P).
// K-loop software-pipelined: ring-2 A (LDS) + ring-3 B (global), pinned with
// sched_barrier(0) per step so the scheduler cannot collapse the ring.
__global__ __launch_bounds__(512, 2) void k2_mfma(
    const unsigned short* __restrict__ Xm0, const unsigned short* __restrict__ Xm1,
    const unsigned short* __restrict__ Xm2,
    const unsigned short* __restrict__ Bn, const unsigned short* __restrict__ Cn,
    const unsigned short* __restrict__ Bt, const unsigned short* __restrict__ Ct,
    const float* __restrict__ A, const float* __restrict__ Bm,
    const float* __restrict__ rowterm, const float* __restrict__ colterm,
    float* __restrict__ mrow, float* __restrict__ out) {
  __shared__ __align__(16) unsigned char smem[65536];
  unsigned short* A_lds = (unsigned short*)smem;        // phase1: 64x512 bf16 swizzled
  unsigned short* P_lds = (unsigned short*)smem;        // phase2: 64x512 bf16 swizzled
  float* sm_m = (float*)smem;                            // softmax: 8x64 (aliases, fenced)
  float* sm_l = (float*)(smem + 2048);                   // softmax: 8x64

  int tid = threadIdx.x;
  int bid0 = blockIdx.x;
  // bijective XCD remap: xcd = bid0&7 owns 24 consecutive logical blocks
  // = 3 full (p,b) groups of 8 row-blocks -> 3MB Yn+Yt resident per XCD L2.
  int bid = (bid0 & 7) * 24 + (bid0 >> 3);
  int p = bid >> 6;            // 3
  int b = (bid >> 3) & 7;      // 8
  int rb = bid & 7;            // 8 row-blocks of 64
  int i0 = rb * 64;

  const unsigned short* Xmp = (p == 0) ? Xm0 : ((p == 1) ? Xm1 : Xm2);
  const unsigned short* Yn  = (p == 0) ? Bn : Cn;
  const unsigned short* Yt  = (p == 0) ? Bt : Ct;
  const float* X = (p == 2) ? Bm : A;

  int wc = tid >> 6;           // wave 0..7 -> 64-col slice
  int lane = tid & 63;
  int n16 = lane & 15, q = lane >> 4;
  int e8 = n16 & 7;

  // ---- Stage A rows i0..i0+63 into LDS, coalesced, chunk-XOR swizzled ----
#pragma unroll
  for (int j = 0; j < 8; ++j) {
    int idx = j * 512 + tid;
    int row = idx >> 6;          // 0..63
    int cc = idx & 63;           // 16B chunk within row
    short8 v = *(const short8*)(Xmp + ((size_t)(b * LL + i0 + row)) * HH + cc * 8);
    *(short8*)&A_lds[row * 512 + (cc ^ (row & 7)) * 8] = v;
  }
  __syncthreads();

  // ---- Phase 1: S[64 x 512] = Xm @ Yn^T, wave wc owns cols wc*64.. ----
  const unsigned short* br0 = Yn + ((size_t)(b * LL + wc * 64 + n16)) * HH + q * 8;
  const unsigned short* br1 = br0 + 16 * HH;
  const unsigned short* br2 = br0 + 32 * HH;
  const unsigned short* br3 = br0 + 48 * HH;

  floatx4 acc[4][4] = {};
  short8 Ax0[4], Ax1[4], Bx0[4], Bx1[4], Bx2[4];

#define LA(AF, kk) do { int ch_ = (((kk) * 4 + q) ^ e8) * 8; \
    AF[0] = *(const short8*)&A_lds[(n16)      * 512 + ch_]; \
    AF[1] = *(const short8*)&A_lds[(16 + n16) * 512 + ch_]; \
    AF[2] = *(const short8*)&A_lds[(32 + n16) * 512 + ch_]; \
    AF[3] = *(const short8*)&A_lds[(48 + n16) * 512 + ch_]; } while (0)
#define LB1(BF, kk) do { const int k0_ = (kk) * 32; \
    BF[0] = *(const short8*)(br0 + k0_); \
    BF[1] = *(const short8*)(br1 + k0_); \
    BF[2] = *(const short8*)(br2 + k0_); \
    BF[3] = *(const short8*)(br3 + k0_); } while (0)
#define MF1(AF, BF) do { \
    acc[0][0]=MM(AF[0],BF[0],acc[0][0],0,0,0); acc[0][1]=MM(AF[0],BF[1],acc[0][1],0,0,0); \
    acc[0][2]=MM(AF[0],BF[2],acc[0][2],0,0,0); acc[0][3]=MM(AF[0],BF[3],acc[0][3],0,0,0); \
    acc[1][0]=MM(AF[1],BF[0],acc[1][0],0,0,0); acc[1][1]=MM(AF[1],BF[1],acc[1][1],0,0,0); \
    acc[1][2]=MM(AF[1],BF[2],acc[1][2],0,0,0); acc[1][3]=MM(AF[1],BF[3],acc[1][3],0,0,0); \
    acc[2][0]=MM(AF[2],BF[0],acc[2][0],0,0,0); acc[2][1]=MM(AF[2],BF[1],acc[2][1],0,0,0); \
    acc[2][2]=MM(AF[2],BF[2],acc[2][2],0,0,0); acc[2][3]=MM(AF[2],BF[3],acc[2][3],0,0,0); \
    acc[3][0]=MM(AF[3],BF[0],acc[3][0],0,0,0); acc[3][1]=MM(AF[3],BF[1],acc[3][1],0,0,0); \
    acc[3][2]=MM(AF[3],BF[2],acc[3][2],0,0,0); acc[3][3]=MM(AF[3],BF[3],acc[3][3],0,0,0); } while (0)

  LB1(Bx0, 0); LB1(Bx1, 1); LB1(Bx2, 2); LA(Ax0, 0); LA(Ax1, 1); SB();
  MF1(Ax0, Bx0); LA(Ax0, 2);  LB1(Bx0, 3);  SB();
  MF1(Ax1, Bx1); LA(Ax1, 3);  LB1(Bx1, 4);  SB();
  MF1(Ax0, Bx2); LA(Ax0, 4);  LB1(Bx2, 5);  SB();
  MF1(Ax1, Bx0); LA(Ax1, 5);  LB1(Bx0, 6);  SB();
  MF1(Ax0, Bx1); LA(Ax0, 6);  LB1(Bx1, 7);  SB();
  MF1(Ax1, Bx2); LA(Ax1, 7);  LB1(Bx2, 8);  SB();
  MF1(Ax0, Bx0); LA(Ax0, 8);  LB1(Bx0, 9);  SB();
  MF1(Ax1, Bx1); LA(Ax1, 9);  LB1(Bx1, 10); SB();
  MF1(Ax0, Bx2); LA(Ax0, 10); LB1(Bx2, 11); SB();
  MF1(Ax1, Bx0); LA(Ax1, 11); LB1(Bx0, 12); SB();
  MF1(Ax0, Bx1); LA(Ax0, 12); LB1(Bx1, 13); SB();
  MF1(Ax1, Bx2); LA(Ax1, 13); LB1(Bx2, 14); SB();
  MF1(Ax0, Bx0); LA(Ax0, 14); LB1(Bx0, 15); SB();
  MF1(Ax1, Bx1); LA(Ax1, 15); SB();
  MF1(Ax0, Bx2); SB();
  MF1(Ax1, Bx0);
#undef LA
#undef LB1
#undef MF1

  __syncthreads();   // all A_lds reads done -> sm region may be written

  // ---- Softmax over 64 rows: per-wave stats + 8-wave LDS combine ----
  float rtv[4][4], ctv[4], mh[4][4], ml[4][4], rinv[4][4];
  {
    const float* rtp = rowterm + (p * BB + b) * LL + i0 + q * 4;
#pragma unroll
    for (int rt = 0; rt < 4; ++rt)
#pragma unroll
      for (int r = 0; r < 4; ++r) rtv[rt][r] = rtp[rt * 16 + r];
    const float* ctp = colterm + (p * BB + b) * LL + wc * 64 + n16;
#pragma unroll
    for (int f = 0; f < 4; ++f) ctv[f] = ctp[f * 16];
  }
#pragma unroll
  for (int rt = 0; rt < 4; ++rt)
#pragma unroll
    for (int r = 0; r < 4; ++r) {
      float m = -1e30f;
#pragma unroll
      for (int f = 0; f < 4; ++f) {
        float v = acc[rt][f][r] + rtv[rt][r] + ctv[f];
        acc[rt][f][r] = v;
        m = fmaxf(m, v);
      }
      m = fmaxf(m, __shfl_xor(m, 1, 64));
      m = fmaxf(m, __shfl_xor(m, 2, 64));
      m = fmaxf(m, __shfl_xor(m, 4, 64));
      m = fmaxf(m, __shfl_xor(m, 8, 64));
      mh[rt][r] = m;
    }
  if (n16 == 0) {
#pragma unroll
    for (int rt = 0; rt < 4; ++rt)
#pragma unroll
      for (int r = 0; r < 4; ++r) sm_m[wc * 64 + rt * 16 + q * 4 + r] = mh[rt][r];
  }
  __syncthreads();
#pragma unroll
  for (int rt = 0; rt < 4; ++rt)
#pragma unroll
    for (int r = 0; r < 4; ++r) {
      float m = mh[rt][r];
#pragma unroll
      for (int k = 0; k < 8; ++k) m = fmaxf(m, sm_m[k * 64 + rt * 16 + q * 4 + r]);
      mh[rt][r] = m;
      float l = 0.f;
#pragma unroll
      for (int f = 0; f < 4; ++f) {
        float pv = __expf(acc[rt][f][r] - m);
        acc[rt][f][r] = pv;
        l += pv;
      }
      l += __shfl_xor(l, 1, 64);
      l += __shfl_xor(l, 2, 64);
      l += __shfl_xor(l, 4, 64);
      l += __shfl_xor(l, 8, 64);
      ml[rt][r] = l;
    }
  if (n16 == 0) {
#pragma unroll
    for (int rt = 0; rt < 4; ++rt)
#pragma unroll
      for (int r = 0; r < 4; ++r) sm_l[wc * 64 + rt * 16 + q * 4 + r] = ml[rt][r];
    if (wc == 0) {
#pragma unroll
      for (int rt = 0; rt < 4; ++rt)
#pragma unroll
        for (int r = 0; r < 4; ++r)
          mrow[(p * BB + b) * LL + i0 + rt * 16 + q * 4 + r] = mh[rt][r];
    }
  }
  __syncthreads();
#pragma unroll
  for (int rt = 0; rt < 4; ++rt)
#pragma unroll
    for (int r = 0; r < 4; ++r) {
      float lf = 0.f;
#pragma unroll
      for (int k = 0; k < 8; ++k) lf += sm_l[k * 64 + rt * 16 + q * 4 + r];
      rinv[rt][r] = 1.f / lf;
    }
  __syncthreads();   // all sm_l reads done -> P may overwrite the region

  // ---- P -> LDS (bf16, unnormalized, XOR-swizzled 8-short chunks) ----
#pragma unroll
  for (int f = 0; f < 4; ++f) {
    int c = wc * 8 + f * 2 + (n16 >> 3);
#pragma unroll
    for (int rt = 0; rt < 4; ++rt)
#pragma unroll
      for (int r = 0; r < 4; ++r) {
        int row = rt * 16 + q * 4 + r;
        int pc = c ^ (row & 7);
        P_lds[row * 512 + pc * 8 + e8] = f2bf(acc[rt][f][r]);
      }
  }
  __syncthreads();

  // ---- Phase 2: O[64 x 512] = P @ Y (B from Yt), same pipelined schedule ----
  const unsigned short* tr0 = Yt + ((size_t)(b * LL + wc * 64 + n16)) * HH + q * 8;
  const unsigned short* tr1 = tr0 + 16 * HH;
  const unsigned short* tr2 = tr0 + 32 * HH;
  const unsigned short* tr3 = tr0 + 48 * HH;

  floatx4 oacc[4][4] = {};
  short8 Px0[4], Px1[4], By0[4], By1[4], By2[4];

#define LP(PF, kj) do { int ch_ = (((kj) * 4 + q) ^ e8) * 8; \
    PF[0] = *(const short8*)&P_lds[(n16)      * 512 + ch_]; \
    PF[1] = *(const short8*)&P_lds[(16 + n16) * 512 + ch_]; \
    PF[2] = *(const short8*)&P_lds[(32 + n16) * 512 + ch_]; \
    PF[3] = *(const short8*)&P_lds[(48 + n16) * 512 + ch_]; } while (0)
#define LB2(BF, kj) do { const int j0_ = (kj) * 32; \
    BF[0] = *(const short8*)(tr0 + j0_); \
    BF[1] = *(const short8*)(tr1 + j0_); \
    BF[2] = *(const short8*)(tr2 + j0_); \
    BF[3] = *(const short8*)(tr3 + j0_); } while (0)
#define MF2(PF, BF) do { \
    oacc[0][0]=MM(PF[0],BF[0],oacc[0][0],0,0,0); oacc[0][1]=MM(PF[0],BF[1],oacc[0][1],0,0,0); \
    oacc[0][2]=MM(PF[0],BF[2],oacc[0][2],0,0,0); oacc[0][3]=MM(PF[0],BF[3],oacc[0][3],0,0,0); \
    oacc[1][0]=MM(PF[1],BF[0],oacc[1][0],0,0,0); oacc[1][1]=MM(PF[1],BF[1],oacc[1][1],0,0,0); \
    oacc[1][2]=MM(PF[1],BF[2],oacc[1][2],0,0,0); oacc[1][3]=MM(PF[1],BF[3],oacc[1][3],0,0,0); \
    oacc[2][0]=MM(PF[2],BF[0],oacc[2][0],0,0,0); oacc[2][1]=MM(PF[2],BF[1],oacc[2][1],0,0,0); \
    oacc[2][2]=MM(PF[2],BF[2],oacc[2][2],0,0,0); oacc[2][3]=MM(PF[2],BF[3],oacc[2][3],0,0,0); \
    oacc[3][0]=MM(PF[3],BF[0],oacc[3][0],0,0,0); oacc[3][1]=MM(PF[3],BF[1],oacc[3][1],0,0,0); \
    oacc[3][2]=MM(PF[3],BF[2],oacc[3][2],0,0,0); oacc[3][3]=MM(PF[3],BF[3],oacc[3][3],0,0,0); } while (0)

  LB2(By0, 0); LB2(By1, 1); LB2(By2, 2); LP(Px0, 0); LP(Px1, 1); SB();
  MF2(Px0, By0); LP(Px0, 2);  LB2(By0, 3);  SB();
  MF2(Px1, By1); LP(Px1, 3);  LB2(By1, 4);  SB();
  MF2(Px0, By2); LP(Px0, 4);  LB2(By2, 5);  SB();
  MF2(Px1, By0); LP(Px1, 5);  LB2(By0, 6);  SB();
  MF2(Px0, By1); LP(Px0, 6);  LB2(By1, 7);  SB();
  MF2(Px1, By2); LP(Px1, 7);  LB2(By2, 8);  SB();
  MF2(Px0, By0); LP(Px0, 8);  LB2(By0, 9);  SB();
  MF2(Px1, By1); LP(Px1, 9);  LB2(By1, 10); SB();
  MF2(Px0, By2); LP(Px0, 10); LB2(By2, 11); SB();
  MF2(Px1, By0); LP(Px1, 11); LB2(By0, 12); SB();
  MF2(Px0, By1); LP(Px0, 12); LB2(By1, 13); SB();
  MF2(Px1, By2); LP(Px1, 13); LB2(By2, 14); SB();
  MF2(Px0, By0); LP(Px0, 14); LB2(By0, 15); SB();
  MF2(Px1, By1); LP(Px1, 15); SB();
  MF2(Px0, By2); SB();
  MF2(Px1, By0);
#undef LP
#undef LB2
#undef MF2

  // ---- Epilogue ----
  int secoff, colbase;
  if      (p == 0) { secoff = 0;   colbase = 512;  }
  else if (p == 1) { secoff = 0;   colbase = 1024; }
  else             { secoff = 512; colbase = 1024; }

#pragma unroll
  for (int f = 0; f < 4; ++f) {
    int d = wc * 64 + f * 16 + n16;
#pragma unroll
    for (int rt = 0; rt < 4; ++rt)
#pragma unroll
      for (int r = 0; r < 4; ++r) {
        int ig = i0 + rt * 16 + q * 4 + r;
        float val = oacc[rt][f][r] * rinv[rt][r];
        size_t ob = ((size_t)b * 1536 + secoff + ig) * 2560;
        out[ob + colbase + d] = val;
        out[ob + colbase + 1024 + d] = X[((size_t)b * LL + ig) * HH + d] * val;
      }
  }
}

// ---------------- K3: beta softmax + weighted row-sum (192 blocks) ----------------
__global__ __launch_bounds__(256) void k3_beta(
    const float* __restrict__ A, const float* __restrict__ Bm,
    const float* __restrict__ mrow, float* __restrict__ vvec) {
  __shared__ float red[256];
  __shared__ float beta[LL];
  __shared__ float s_inv;
  int blk = blockIdx.x;           // 192
  int p = blk >> 6;
  int rem2 = blk & 63;
  int b = rem2 >> 3;
  int dch = rem2 & 7;
  int tid = threadIdx.x;
  const float* m = mrow + (p * BB + b) * LL;
  red[tid] = fmaxf(m[tid], m[tid + 256]);
  __syncthreads();
  for (int off = 128; off; off >>= 1) {
    if (tid < off) red[tid] = fmaxf(red[tid], red[tid + off]);
    __syncthreads();
  }
  float mx = red[0];
  __syncthreads();
  float e0 = __expf(m[tid] - mx), e1 = __expf(m[tid + 256] - mx);
  beta[tid] = e0; beta[tid + 256] = e1;
  red[tid] = e0 + e1;
  __syncthreads();
  for (int off = 128; off; off >>= 1) {
    if (tid < off) red[tid] += red[tid + off];
    __syncthreads();
  }
  if (tid == 0) s_inv = 1.f / red[0];
  __syncthreads();
  const float* Xb = ((p == 2) ? Bm : A) + (size_t)b * LL * HH;
  int d = dch * 64 + (tid & 63);
  int ig = tid >> 6;
  float acc = 0.f;
#pragma unroll 8
  for (int i = ig * 128; i < ig * 128 + 128; ++i)
    acc += beta[i] * Xb[(size_t)i * HH + d];
  red[tid] = acc;
  __syncthreads();
  if (tid < 64) {
    float s = red[tid] + red[tid + 64] + red[tid + 128] + red[tid + 192];
    vvec[(p * BB + b) * HH + dch * 64 + tid] = s * s_inv;
  }
}

// ---------------- K4: finalize, float4, only needed slices ----------------
__global__ __launch_bounds__(256) void k4_finalize(
    const float* __restrict__ A, const float* __restrict__ Bm, const float* __restrict__ C,
    const float* __restrict__ vvec, float* __restrict__ out) {
  unsigned int idx = blockIdx.x * 256 + threadIdx.x;   // 4718592 threads
  int f4 = idx & 127;
  int i  = (idx >> 7) & 511;
  unsigned int ub = idx >> 16;
  unsigned int u = ub % 9;
  unsigned int b = ub / 9;
  int sec, slice;
  if (u == 0)      { sec = 0; slice = 0; }
  else if (u <= 3) { sec = 1; slice = (u == 1) ? 0 : (u == 2 ? 1 : 3); }
  else             { sec = 2; slice = (int)u - 4; }
  int cc = f4 * 4;
  const float* enc = sec == 0 ? A : (sec == 1 ? Bm : C);
  float4 val;
  if (slice == 0) {
    val = *(const float4*)(enc + ((size_t)b * LL + i) * HH + cc);
  } else {
    int vp = (sec == 1) ? 0 : ((slice == 1 || slice == 3) ? 1 : 2);
    float4 v = *(const float4*)(vvec + (vp * BB + b) * HH + cc);
    if (slice <= 2) {
      val = v;
    } else {
      float4 e = *(const float4*)(enc + ((size_t)b * LL + i) * HH + cc);
      val.x = e.x * v.x; val.y = e.y * v.y; val.z = e.z * v.z; val.w = e.w * v.w;
    }
  }
  *(float4*)(out + ((size_t)b * 1536 + sec * 512 + i) * 2560 + slice * 512 + cc) = val;
}

extern "C" void kernel_launch(void* const* d_in, const int* in_sizes, int n_in,
                              void* d_out, int out_size, void* d_ws, size_t ws_size,
                              hipStream_t stream) {
  const float* A  = (const float*)d_in[0];
  const float* Bm = (const float*)d_in[1];
  const float* C  = (const float*)d_in[2];
  const float* w0 = (const float*)d_in[3];
  const float* w1 = (const float*)d_in[4];
  const float* w2 = (const float*)d_in[5];
  float* out = (float*)d_out;

  float* wsf = (float*)d_ws;
  float* rowterm = wsf;
  float* colterm = wsf + 12288;
  float* mrow    = wsf + 24576;
  float* vvec    = wsf + 36864;
  unsigned short* wss = (unsigned short*)(wsf + 49152);
  const size_t MSZ = (size_t)BB * LL * HH;     // 2,097,152
  unsigned short* Bn  = wss;
  unsigned short* Cn  = wss + MSZ;
  unsigned short* Bt  = wss + 2 * MSZ;
  unsigned short* Ct  = wss + 3 * MSZ;
  unsigned short* Xm0 = wss + 4 * MSZ;
  unsigned short* Xm1 = wss + 5 * MSZ;
  unsigned short* Xm2 = wss + 6 * MSZ;

  k0_conv<<<1024, 256, 0, stream>>>(Bm, C, Bn, Cn, Bt, Ct);
  k0_xm<<<3072, 256, 0, stream>>>(A, Bm, w0, w1, w2, Xm0, Xm1, Xm2);
  k1_terms<<<3072, 256, 0, stream>>>(A, Bm, C, w0, w1, w2, rowterm, colterm);
  k2_mfma<<<192, 512, 0, stream>>>(Xm0, Xm1, Xm2, Bn, Cn, Bt, Ct, A, Bm,
                                   rowterm, colterm, mrow, out);
  k3_beta<<<192, 256, 0, stream>>>(A, Bm, mrow, vvec);
  k4_finalize<<<18432, 256, 0, stream>>>(A, Bm, C, vvec, out);
}